// Round 2
// baseline (177.786 us; speedup 1.0000x reference)
//
#include <hip/hip_runtime.h>

// OptPosEncBatch: per-point multi-feature 1D-linear codebook interpolation.
// coords [B=8, P=65536, F=3] f32, idx [B] i32, shape_code [C=64, S*F*CN=3072] f32
// out [B, P, C=64] f32.
//
// Strategy: per block, stage the batch's 192x64 transposed codebook slice
// (48 KB) into LDS; each point's output = sum of 6 weighted 64-float LDS rows.
// 16 lanes/point x 4 channels/lane -> ds_read_b128 gathers + float4 stores.

#define CODE_NUM 64
#define NFEAT 3
#define NCHAN 64
#define NB 8
#define NP 65536
#define SLICE (CODE_NUM * NFEAT)      // 192 rows in the per-batch slice
#define ROW_STRIDE 3072               // SHAPE_NUM * NFEAT * CODE_NUM
#define NTHREADS 512
#define BLOCKS_PER_BATCH 64
#define PTS_PER_BLOCK (NP / BLOCKS_PER_BATCH)   // 1024
#define PTS_PER_ITER (NTHREADS / 16)            // 32

__global__ __launch_bounds__(NTHREADS)
void posenc_kernel(const float* __restrict__ coords,
                   const int* __restrict__ idx,
                   const float* __restrict__ shape_code,
                   float* __restrict__ out) {
    __shared__ float lds[SLICE * NCHAN];   // [row][channel], 49152 B

    const int bx    = blockIdx.x;
    const int b     = bx >> 6;                  // batch
    const int chunk = (bx & (BLOCKS_PER_BATCH - 1)) * PTS_PER_BLOCK;
    const int tid   = threadIdx.x;

    const int base = idx[b] * SLICE;            // element offset within a codebook row

    // --- stage shape_code[c][base .. base+191] -> lds[j][c] ---
    // lane c streams its own row segment (768 B, L1-amortized float4 reads);
    // LDS writes: all 64 lanes same j, banks c%32 -> 2-way alias (free).
    {
        const int c      = tid & 63;
        const int jchunk = tid >> 6;            // 0..7
        const float* src = shape_code + (size_t)c * ROW_STRIDE + base;
        #pragma unroll
        for (int jv = jchunk; jv < SLICE / 4; jv += NTHREADS / 64) {
            const float4 v = *reinterpret_cast<const float4*>(src + jv * 4);
            lds[(jv * 4 + 0) * NCHAN + c] = v.x;
            lds[(jv * 4 + 1) * NCHAN + c] = v.y;
            lds[(jv * 4 + 2) * NCHAN + c] = v.z;
            lds[(jv * 4 + 3) * NCHAN + c] = v.w;
        }
    }
    __syncthreads();

    const int gl   = tid & 15;                  // channel group: channels gl*4 .. gl*4+3
    const int pofs = tid >> 4;                  // 0..31: point offset within iteration
    const size_t bp0 = (size_t)b * NP;

    for (int it = 0; it < PTS_PER_BLOCK / PTS_PER_ITER; ++it) {
        const int p = chunk + it * PTS_PER_ITER + pofs;
        const float* cp = coords + (bp0 + p) * NFEAT;

        const float x0 = cp[0];
        const float x1 = cp[1];
        const float x2 = cp[2];

        float4 acc = make_float4(0.f, 0.f, 0.f, 0.f);

        #pragma unroll
        for (int f = 0; f < NFEAT; ++f) {
            const float xf = (f == 0) ? x0 : (f == 1) ? x1 : x2;
            const float g  = (xf + 1.0f) * ((CODE_NUM - 1) * 0.5f);
            int c0 = (int)floorf(g);
            c0 = max(0, min(c0, CODE_NUM - 2));   // safety; identical math at g->63
            const float w1 = g - (float)c0;
            const float w0 = 1.0f - w1;

            const int r = (f * CODE_NUM + c0) * NCHAN + gl * 4;
            const float4 v0 = *reinterpret_cast<const float4*>(&lds[r]);
            const float4 v1 = *reinterpret_cast<const float4*>(&lds[r + NCHAN]);

            acc.x = fmaf(w0, v0.x, fmaf(w1, v1.x, acc.x));
            acc.y = fmaf(w0, v0.y, fmaf(w1, v1.y, acc.y));
            acc.z = fmaf(w0, v0.z, fmaf(w1, v1.z, acc.z));
            acc.w = fmaf(w0, v0.w, fmaf(w1, v1.w, acc.w));
        }

        float4* op = reinterpret_cast<float4*>(out + (bp0 + p) * NCHAN + gl * 4);
        *op = acc;
    }
}

extern "C" void kernel_launch(void* const* d_in, const int* in_sizes, int n_in,
                              void* d_out, int out_size, void* d_ws, size_t ws_size,
                              hipStream_t stream) {
    const float* coords     = (const float*)d_in[0];
    const int*   idx        = (const int*)d_in[1];
    const float* shape_code = (const float*)d_in[2];
    float*       out        = (float*)d_out;

    dim3 grid(NB * BLOCKS_PER_BATCH);   // 512 blocks
    dim3 block(NTHREADS);               // 512 threads
    posenc_kernel<<<grid, block, 0, stream>>>(coords, idx, shape_code, out);
}

// Round 3
// 164.486 us; speedup vs baseline: 1.0809x; 1.0809x over previous
//
#include <hip/hip_runtime.h>

// OptPosEncBatch: per-point multi-feature 1D-linear codebook interpolation.
// coords [B=8, P=65536, F=3] f32, idx [B] i32, shape_code [C=64, S*F*CN=3072] f32
// out [B, P, C=64] f32.
//
// R2 analysis: kernel ~75us (absent from rocprof top-5; memsets at 79us), i.e.
// ~3x the 25us write roofline -> latency-bound inner loop (scalar global coord
// loads + un-pipelined LDS gathers). R3 change: stage coords chunk in LDS too
// (coalesced float4, once per block) + unroll 4 for 4 in-flight chains/wave.

#define CODE_NUM 64
#define NFEAT 3
#define NCHAN 64
#define NB 8
#define NP 65536
#define SLICE (CODE_NUM * NFEAT)      // 192 rows in the per-batch slice
#define ROW_STRIDE 3072               // SHAPE_NUM * NFEAT * CODE_NUM
#define NTHREADS 512
#define BLOCKS_PER_BATCH 64
#define PTS_PER_BLOCK (NP / BLOCKS_PER_BATCH)   // 1024
#define PTS_PER_ITER (NTHREADS / 16)            // 32

__global__ __launch_bounds__(NTHREADS, 4)   // 4 waves/EU = 16 waves/CU = 2 blocks/CU
void posenc_kernel(const float* __restrict__ coords,
                   const int* __restrict__ idx,
                   const float* __restrict__ shape_code,
                   float* __restrict__ out) {
    __shared__ float code_lds[SLICE * NCHAN];            // [row][channel], 48 KB
    __shared__ float coord_lds[PTS_PER_BLOCK * NFEAT];   // 12 KB

    const int bx    = blockIdx.x;
    const int b     = bx >> 6;                  // batch
    const int chunk = (bx & (BLOCKS_PER_BATCH - 1)) * PTS_PER_BLOCK;
    const int tid   = threadIdx.x;
    const size_t bp0 = (size_t)b * NP;

    // --- stage this block's coords chunk: 1024 pts x 3 f32 = 768 float4 ---
    // (bp0+chunk)*3*4B is a multiple of 12288 -> 16B-aligned. Coalesced.
    {
        const float4* src = reinterpret_cast<const float4*>(coords + (bp0 + chunk) * NFEAT);
        float4* dst = reinterpret_cast<float4*>(coord_lds);
        #pragma unroll
        for (int i = tid; i < PTS_PER_BLOCK * NFEAT / 4; i += NTHREADS)
            dst[i] = src[i];
    }

    // --- stage shape_code[c][base .. base+191] -> code_lds[j][c] ---
    // lane c streams its own row segment (768 B, L1-amortized float4 reads);
    // LDS writes: all 64 lanes same j, banks c%32 -> 2-way alias (free, m136).
    const int base = idx[b] * SLICE;            // element offset within a codebook row
    {
        const int c      = tid & 63;
        const int jchunk = tid >> 6;            // 0..7
        const float* src = shape_code + (size_t)c * ROW_STRIDE + base;
        #pragma unroll
        for (int jv = jchunk; jv < SLICE / 4; jv += NTHREADS / 64) {
            const float4 v = *reinterpret_cast<const float4*>(src + jv * 4);
            code_lds[(jv * 4 + 0) * NCHAN + c] = v.x;
            code_lds[(jv * 4 + 1) * NCHAN + c] = v.y;
            code_lds[(jv * 4 + 2) * NCHAN + c] = v.z;
            code_lds[(jv * 4 + 3) * NCHAN + c] = v.w;
        }
    }
    __syncthreads();

    const int gl   = tid & 15;                  // channel group: channels gl*4 .. gl*4+3
    const int pofs = tid >> 4;                  // 0..31: point offset within iteration
    float* outg = out + (bp0 + chunk) * NCHAN + gl * 4;

    #pragma unroll 4
    for (int it = 0; it < PTS_PER_BLOCK / PTS_PER_ITER; ++it) {
        const int lp = it * PTS_PER_ITER + pofs;     // local point index 0..1023

        // broadcast LDS reads (16 lanes same addr); 4 groups hit 4 distinct banks
        const float x0 = coord_lds[lp * 3 + 0];
        const float x1 = coord_lds[lp * 3 + 1];
        const float x2 = coord_lds[lp * 3 + 2];

        float4 acc = make_float4(0.f, 0.f, 0.f, 0.f);

        #pragma unroll
        for (int f = 0; f < NFEAT; ++f) {
            const float xf = (f == 0) ? x0 : (f == 1) ? x1 : x2;
            const float g  = (xf + 1.0f) * ((CODE_NUM - 1) * 0.5f);
            int c0 = (int)floorf(g);
            c0 = max(0, min(c0, CODE_NUM - 2));   // safety; input domain never clamps
            const float w1 = g - (float)c0;
            const float w0 = 1.0f - w1;

            const int r = (f * CODE_NUM + c0) * NCHAN + gl * 4;
            const float4 v0 = *reinterpret_cast<const float4*>(&code_lds[r]);
            const float4 v1 = *reinterpret_cast<const float4*>(&code_lds[r + NCHAN]);

            acc.x = fmaf(w0, v0.x, fmaf(w1, v1.x, acc.x));
            acc.y = fmaf(w0, v0.y, fmaf(w1, v1.y, acc.y));
            acc.z = fmaf(w0, v0.z, fmaf(w1, v1.z, acc.z));
            acc.w = fmaf(w0, v0.w, fmaf(w1, v1.w, acc.w));
        }

        // wave writes 4 contiguous 256B point-rows = 1KB coalesced
        *reinterpret_cast<float4*>(outg + (size_t)lp * NCHAN) = acc;
    }
}

extern "C" void kernel_launch(void* const* d_in, const int* in_sizes, int n_in,
                              void* d_out, int out_size, void* d_ws, size_t ws_size,
                              hipStream_t stream) {
    const float* coords     = (const float*)d_in[0];
    const int*   idx        = (const int*)d_in[1];
    const float* shape_code = (const float*)d_in[2];
    float*       out        = (float*)d_out;

    dim3 grid(NB * BLOCKS_PER_BATCH);   // 512 blocks
    dim3 block(NTHREADS);               // 512 threads
    posenc_kernel<<<grid, block, 0, stream>>>(coords, idx, shape_code, out);
}

// Round 4
// 162.635 us; speedup vs baseline: 1.0932x; 1.0114x over previous
//
#include <hip/hip_runtime.h>

// OptPosEncBatch: per-point multi-feature 1D-linear codebook interpolation.
// coords [B=8, P=65536, F=3] f32, idx [B] i32, shape_code [C=64, S*F*CN=3072] f32
// out [B, P, C=64] f32.
//
// R3 analysis: kernel ~63us vs ~21us write floor / ~19us LDS-pipe floor ->
// latency-bound; unroll-4 under the 128-VGPR cap (launch_bounds 512,4) likely
// serialized or spilled. R4: explicit 1-deep software pipeline (prefetch
// coords+indices+6x ds_read_b128 for it+1 while FMA/storing it), ~85 VGPR
// steady state, coords padded to float4 (one broadcast b128 per iter).

#define CODE_NUM 64
#define NFEAT 3
#define NCHAN 64
#define NB 8
#define NP 65536
#define SLICE (CODE_NUM * NFEAT)      // 192 rows in the per-batch slice
#define ROW_STRIDE 3072               // SHAPE_NUM * NFEAT * CODE_NUM
#define NTHREADS 512
#define BLOCKS_PER_BATCH 64
#define PTS_PER_BLOCK (NP / BLOCKS_PER_BATCH)   // 1024
#define PTS_PER_ITER (NTHREADS / 16)            // 32
#define NIT (PTS_PER_BLOCK / PTS_PER_ITER)      // 32

__global__ __launch_bounds__(NTHREADS, 4)   // 4 waves/EU = 16 waves/CU = 2 blocks/CU
void posenc_kernel(const float* __restrict__ coords,
                   const int* __restrict__ idx,
                   const float* __restrict__ shape_code,
                   float* __restrict__ out) {
    __shared__ float  code_lds[SLICE * NCHAN];   // [row][channel], 48 KB
    __shared__ float4 coord_lds[PTS_PER_BLOCK];  // padded xyz_, 16 KB

    const int bx    = blockIdx.x;
    const int b     = bx >> 6;                  // batch
    const int chunk = (bx & (BLOCKS_PER_BATCH - 1)) * PTS_PER_BLOCK;
    const int tid   = threadIdx.x;
    const size_t bp0 = (size_t)b * NP;

    // --- stage coords chunk, padded to float4 (w unused). 12 KB read, once. ---
    {
        const float* src = coords + (bp0 + chunk) * NFEAT;
        #pragma unroll
        for (int p = tid; p < PTS_PER_BLOCK; p += NTHREADS)
            coord_lds[p] = make_float4(src[p * 3 + 0], src[p * 3 + 1], src[p * 3 + 2], 0.f);
    }

    // --- stage shape_code[c][base .. base+191] -> code_lds[j][c] ---
    // lane c streams its own row segment; LDS writes 2-way bank alias (free).
    const int base = idx[b] * SLICE;
    {
        const int c      = tid & 63;
        const int jchunk = tid >> 6;            // 0..7
        const float* src = shape_code + (size_t)c * ROW_STRIDE + base;
        #pragma unroll
        for (int jv = jchunk; jv < SLICE / 4; jv += NTHREADS / 64) {
            const float4 v = *reinterpret_cast<const float4*>(src + jv * 4);
            code_lds[(jv * 4 + 0) * NCHAN + c] = v.x;
            code_lds[(jv * 4 + 1) * NCHAN + c] = v.y;
            code_lds[(jv * 4 + 2) * NCHAN + c] = v.z;
            code_lds[(jv * 4 + 3) * NCHAN + c] = v.w;
        }
    }
    __syncthreads();

    const int gl   = tid & 15;                  // channel group: channels gl*4..gl*4+3
    const int pofs = tid >> 4;                  // 0..31: point offset within iteration
    float* outg = out + (bp0 + chunk) * NCHAN + gl * 4;

    // loop-invariant per-feature LDS float-offsets at this lane's channels
    const int inv0 = 0 * CODE_NUM * NCHAN + gl * 4;
    const int inv1 = 1 * CODE_NUM * NCHAN + gl * 4;
    const int inv2 = 2 * CODE_NUM * NCHAN + gl * 4;

#define LOAD_IT(IT, A0, A1, B0, B1, C0, C1, WA, WB, WC)                        \
    {                                                                          \
        const float4 xyz = coord_lds[(IT) * PTS_PER_ITER + pofs];              \
        const float g0 = fmaf(xyz.x, 31.5f, 31.5f);                            \
        const float g1 = fmaf(xyz.y, 31.5f, 31.5f);                            \
        const float g2 = fmaf(xyz.z, 31.5f, 31.5f);                            \
        int i0 = (int)floorf(g0); i0 = max(0, min(i0, CODE_NUM - 2));          \
        int i1 = (int)floorf(g1); i1 = max(0, min(i1, CODE_NUM - 2));          \
        int i2 = (int)floorf(g2); i2 = max(0, min(i2, CODE_NUM - 2));          \
        WA = g0 - (float)i0;                                                   \
        WB = g1 - (float)i1;                                                   \
        WC = g2 - (float)i2;                                                   \
        const float* r0 = &code_lds[inv0 + i0 * NCHAN];                        \
        const float* r1 = &code_lds[inv1 + i1 * NCHAN];                        \
        const float* r2 = &code_lds[inv2 + i2 * NCHAN];                        \
        A0 = *reinterpret_cast<const float4*>(r0);                             \
        A1 = *reinterpret_cast<const float4*>(r0 + NCHAN);                     \
        B0 = *reinterpret_cast<const float4*>(r1);                             \
        B1 = *reinterpret_cast<const float4*>(r1 + NCHAN);                     \
        C0 = *reinterpret_cast<const float4*>(r2);                             \
        C1 = *reinterpret_cast<const float4*>(r2 + NCHAN);                     \
    }

#define COMPUTE_STORE(IT, A0, A1, B0, B1, C0, C1, WA, WB, WC)                  \
    {                                                                          \
        const float wa0 = 1.0f - WA, wb0 = 1.0f - WB, wc0 = 1.0f - WC;         \
        float4 acc;                                                            \
        acc.x = fmaf(wa0, A0.x, WA * A1.x);                                    \
        acc.y = fmaf(wa0, A0.y, WA * A1.y);                                    \
        acc.z = fmaf(wa0, A0.z, WA * A1.z);                                    \
        acc.w = fmaf(wa0, A0.w, WA * A1.w);                                    \
        acc.x = fmaf(wb0, B0.x, fmaf(WB, B1.x, acc.x));                        \
        acc.y = fmaf(wb0, B0.y, fmaf(WB, B1.y, acc.y));                        \
        acc.z = fmaf(wb0, B0.z, fmaf(WB, B1.z, acc.z));                        \
        acc.w = fmaf(wb0, B0.w, fmaf(WB, B1.w, acc.w));                        \
        acc.x = fmaf(wc0, C0.x, fmaf(WC, C1.x, acc.x));                        \
        acc.y = fmaf(wc0, C0.y, fmaf(WC, C1.y, acc.y));                        \
        acc.z = fmaf(wc0, C0.z, fmaf(WC, C1.z, acc.z));                        \
        acc.w = fmaf(wc0, C0.w, fmaf(WC, C1.w, acc.w));                        \
        *reinterpret_cast<float4*>(outg + (size_t)((IT) * PTS_PER_ITER + pofs) * NCHAN) = acc; \
    }

    // explicit 1-deep pipeline: prefetch it+1 while computing it
    float4 A0, A1, B0, B1, C0, C1;
    float  wA, wB, wC;
    LOAD_IT(0, A0, A1, B0, B1, C0, C1, wA, wB, wC);

    #pragma unroll 1
    for (int it = 0; it < NIT - 1; ++it) {
        const float4 a0 = A0, a1 = A1, b0 = B0, b1 = B1, c0 = C0, c1 = C1;
        const float  wa = wA, wb = wB, wc = wC;
        LOAD_IT(it + 1, A0, A1, B0, B1, C0, C1, wA, wB, wC);   // in flight...
        COMPUTE_STORE(it, a0, a1, b0, b1, c0, c1, wa, wb, wc); // ...over this
    }
    COMPUTE_STORE(NIT - 1, A0, A1, B0, B1, C0, C1, wA, wB, wC);

#undef LOAD_IT
#undef COMPUTE_STORE
}

extern "C" void kernel_launch(void* const* d_in, const int* in_sizes, int n_in,
                              void* d_out, int out_size, void* d_ws, size_t ws_size,
                              hipStream_t stream) {
    const float* coords     = (const float*)d_in[0];
    const int*   idx        = (const int*)d_in[1];
    const float* shape_code = (const float*)d_in[2];
    float*       out        = (float*)d_out;

    dim3 grid(NB * BLOCKS_PER_BATCH);   // 512 blocks
    dim3 block(NTHREADS);               // 512 threads
    posenc_kernel<<<grid, block, 0, stream>>>(coords, idx, shape_code, out);
}